// Round 5
// baseline (1630.671 us; speedup 1.0000x reference)
//
#include <hip/hip_runtime.h>
#include <hip/hip_bf16.h>
#include <type_traits>

using u16 = unsigned short;

static constexpr int BG   = 16384;          // graphs
static constexpr int NPG  = 11;             // nodes per graph
static constexpr int NTOT = BG * NPG;       // 180224 nodes
static constexpr int EDG  = NTOT * 8;       // 1441792 edges

typedef __attribute__((ext_vector_type(8))) short short8;   // 8 bf16 (4 VGPRs)
typedef __attribute__((ext_vector_type(4))) float f32x4;

__device__ __forceinline__ u16 f2bf(float f) {              // RNE fp32->bf16
  unsigned u = __float_as_uint(f);
  return (u16)((u + 0x7FFFu + ((u >> 16) & 1u)) >> 16);
}
__device__ __forceinline__ float bf2f(u16 u) { return __uint_as_float(((unsigned)u) << 16); }
__device__ __forceinline__ unsigned pk(float a, float b) {
  return (unsigned)f2bf(a) | ((unsigned)f2bf(b) << 16);
}
__device__ __forceinline__ float fast_sig(float x) {
  return 1.f / (1.f + __expf(-x));
}
__device__ __forceinline__ float fast_tanh(float x) {       // overflow-safe
  float a = fabsf(x);
  float e = __expf(-2.f * a);
  float t = (1.f - e) / (1.f + e);
  return copysignf(t, x);
}
__device__ __forceinline__ float sel4(float a0, float a1, float a2, float a3, int k) {
  float m01 = (k & 1) ? a1 : a0;
  float m23 = (k & 1) ? a3 : a2;
  return (k & 2) ? m23 : m01;
}

// ---------------------------------------------------------------------------
// Persistent fused LSTM: each block owns 64 graphs through ALL 11 timesteps.
// gates = [x_t | h] @ Wp^T (+biasP); Wp rows permuted n' = 4*unit + gate.
// h (bf16) + x_t staged in swizzled LDS; c in registers; B software-pipelined
// (prefetch k0+32 into regs during MFMA). t=0 skips the h half (h0=0).
// Tail: fused ff head  out = (h @ Wf1 + bf1) @ Wf2 + bf2  -> ffout.
// LDS: x 32K + h 32K + B 64K = 128 KB (1 block/CU).
// ---------------------------------------------------------------------------
__global__ __launch_bounds__(512, 2) void lstm_persist(const float* __restrict__ feat,
                                                       const u16* __restrict__ Wp,
                                                       const float* __restrict__ biasP,
                                                       const float* __restrict__ bf1,
                                                       const float* __restrict__ Wf1,
                                                       const float* __restrict__ Wf2,
                                                       const float* __restrict__ bf2,
                                                       float* __restrict__ ffout) {
  __shared__ u16 x_lds[64 * 256];
  __shared__ u16 h_lds[64 * 256];
  __shared__ u16 Blds[1024 * 32];
  const int tid  = threadIdx.x;
  const int lane = tid & 63;
  const int wave = tid >> 6;
  const int q = lane >> 4;
  const int l = lane & 15;
  const int tg = l & 3;
  const int wn = wave * 128;
  const int row0 = blockIdx.x * 64;

  const int br = tid >> 2;            // B-stage row 0..127
  const int sq = tid & 3;             // B-stage k-slot

  float c_reg[4][8] = {};
  float bb[8];
  #pragma unroll
  for (int j = 0; j < 8; ++j) bb[j] = biasP[wn + j * 16 + l];

  for (int t = 0; t < NPG; ++t) {
    const int kmax = t ? 512 : 256;
    // ---- stage x_t (64 x 256 fp32 -> bf16, swizzled) ----
    {
      const int sr = tid >> 3;
      const int kq = (tid & 7) << 5;
      const float* p = feat + (size_t)(row0 + sr) * 2816 + t * 256 + kq;
      #pragma unroll
      for (int c4 = 0; c4 < 4; ++c4) {
        float4 f0 = *(const float4*)(p + c4 * 8);
        float4 f1 = *(const float4*)(p + c4 * 8 + 4);
        uint4 v;
        v.x = pk(f0.x, f0.y); v.y = pk(f0.z, f0.w);
        v.z = pk(f1.x, f1.y); v.w = pk(f1.z, f1.w);
        const int k = kq + c4 * 8;
        const int slot = ((k >> 3) & 3) ^ (sr & 3);
        *(uint4*)&x_lds[sr * 256 + (k & ~31) + slot * 8] = v;
      }
    }
    // ---- stage B k0=0 ----
    #pragma unroll
    for (int i = 0; i < 8; ++i) {
      const int n = br + i * 128;
      uint4 v = *(const uint4*)(Wp + (size_t)n * 512 + sq * 8);
      *(uint4*)&Blds[((n << 2) + (sq ^ (n & 3))) << 3] = v;
    }
    __syncthreads();

    f32x4 acc[4][8] = {};
    for (int k0 = 0; k0 < kmax; k0 += 32) {
      const bool hn = (k0 + 32) < kmax;
      uint4 pf[8];
      if (hn) {
        #pragma unroll
        for (int i = 0; i < 8; ++i)
          pf[i] = *(const uint4*)(Wp + (size_t)(br + i * 128) * 512 + (k0 + 32) + sq * 8);
      }
      // fragments + MFMA
      short8 af[4];
      const u16* abase = (k0 < 256) ? x_lds : h_lds;
      const int kk = (k0 < 256) ? k0 : (k0 - 256);
      #pragma unroll
      for (int i = 0; i < 4; ++i) {
        const int r = i * 16 + l;
        af[i] = *(const short8*)&abase[r * 256 + kk + (q ^ (r & 3)) * 8];
      }
      #pragma unroll
      for (int j = 0; j < 8; ++j) {
        const int n = wn + j * 16 + l;
        short8 bfr = *(const short8*)&Blds[((n << 2) + (q ^ (n & 3))) << 3];
        #pragma unroll
        for (int i = 0; i < 4; ++i)
          acc[i][j] = __builtin_amdgcn_mfma_f32_16x16x32_bf16(af[i], bfr, acc[i][j], 0, 0, 0);
      }
      __syncthreads();
      if (hn) {
        #pragma unroll
        for (int i = 0; i < 8; ++i) {
          const int n = br + i * 128;
          *(uint4*)&Blds[((n << 2) + (sq ^ (n & 3))) << 3] = pf[i];
        }
      }
      __syncthreads();
    }

    // ---- epilogue: gate exchange + pointwise; h -> LDS, c in regs ----
    #pragma unroll
    for (int i = 0; i < 4; ++i) {
      #pragma unroll
      for (int j = 0; j < 8; ++j) {
        const int col = wn + j * 16 + l;
        const int u = col >> 2;
        float gi = 0.f, gf = 0.f, gg = 0.f, go = 0.f;
        #pragma unroll
        for (int r = 0; r < 4; ++r) {
          float v  = acc[i][j][r] + bb[j];
          float x1 = __shfl_xor(v, 1);
          float x2 = __shfl_xor(v, 2);
          float x3 = __shfl_xor(v, 3);
          float cgi = sel4(v, x1, x2, x3, tg);
          float cgf = sel4(v, x1, x2, x3, tg ^ 1);
          float cgg = sel4(v, x1, x2, x3, tg ^ 2);
          float cgo = sel4(v, x1, x2, x3, tg ^ 3);
          const bool mine = (tg == r);
          gi = mine ? cgi : gi;
          gf = mine ? cgf : gf;
          gg = mine ? cgg : gg;
          go = mine ? cgo : go;
        }
        float cn = fast_sig(gf) * c_reg[i][j] + fast_sig(gi) * fast_tanh(gg);
        c_reg[i][j] = cn;
        const int lrow = i * 16 + q * 4 + tg;
        const int slot = ((u >> 3) & 3) ^ (lrow & 3);
        h_lds[lrow * 256 + (u & ~31) + slot * 8 + (u & 7)] = f2bf(fast_sig(go) * fast_tanh(cn));
      }
    }
  }

  // ---- fused ff head: (h @ Wf1 + bf1) @ Wf2 + bf2 ----
  __syncthreads();                        // h_lds final
  float* tmpf = (float*)Blds;             // 64x64 fp32 = 16 KB (aliases Blds)
  {
    const int col = tid & 63, rg = tid >> 6;    // rg 0..7 -> rows rg*8..rg*8+7
    float facc[8];
    #pragma unroll
    for (int m = 0; m < 8; ++m) facc[m] = bf1[col];
    for (int k = 0; k < 256; ++k) {
      const float w = Wf1[k * 64 + col];
      #pragma unroll
      for (int m = 0; m < 8; ++m) {
        const int r = rg * 8 + m;
        const int slot = ((k >> 3) & 3) ^ (r & 3);
        facc[m] += bf2f(h_lds[r * 256 + (k & ~31) + slot * 8 + (k & 7)]) * w;
      }
    }
    __syncthreads();                      // Blds reads long done; safe to alias
    #pragma unroll
    for (int m = 0; m < 8; ++m) tmpf[(rg * 8 + m) * 64 + col] = facc[m];
  }
  __syncthreads();
  if (tid < 128) {
    const int r = tid >> 1, o = tid & 1;
    float s = bf2[o];
    #pragma unroll 8
    for (int j = 0; j < 64; ++j) s += tmpf[r * 64 + j] * Wf2[j * 2 + o];
    ffout[(size_t)(row0 + r) * 2 + o] = s;
  }
}

// ---------------------------------------------------------------------------
// MFMA GEMM: C[M,N] = A[M,K] @ Bt[N,K]^T.  BM=128, BN=256, BK=32, 512 thr.
// AMODE 0: A fp32 row-major (stride K). AMODE 1: A bf16 row-major; in-place
// C==A safe (full row read before epilogue write, full N per row-block).
// ---------------------------------------------------------------------------
template<int AMODE, typename TC>
__global__ __launch_bounds__(512) void gemm_mfma(const float* __restrict__ Af,
                                                 const u16* Ab,
                                                 const u16* __restrict__ Bt,
                                                 TC* C, int N, int K) {
  __shared__ u16 Alds[128 * 32];
  __shared__ u16 Blds[256 * 32];
  const int tid  = threadIdx.x;
  const int lane = tid & 63;
  const int wave = tid >> 6;
  const int q = lane >> 4;
  const int l = lane & 15;
  const int wm = (wave >> 2) * 64;
  const int wn = (wave & 3) * 64;
  const int row0 = blockIdx.y * 128;
  const int col0 = blockIdx.x * 256;

  f32x4 acc[4][4] = {};
  const int sr = tid >> 2;
  const int sq = tid & 3;
  const int aslot = sq ^ (sr & 3);

  for (int k0 = 0; k0 < K; k0 += 32) {
    {
      uint4 v;
      if constexpr (AMODE == 0) {
        const float* p = Af + (size_t)(row0 + sr) * K + k0 + sq * 8;
        float4 f0 = *(const float4*)p;
        float4 f1 = *(const float4*)(p + 4);
        v.x = pk(f0.x, f0.y); v.y = pk(f0.z, f0.w);
        v.z = pk(f1.x, f1.y); v.w = pk(f1.z, f1.w);
      } else {
        v = *(const uint4*)(Ab + (size_t)(row0 + sr) * K + k0 + sq * 8);
      }
      *(uint4*)&Alds[(((sr << 2) + aslot)) << 3] = v;
    }
    #pragma unroll
    for (int i = 0; i < 2; ++i) {
      const int n = sr + i * 128;
      const int slot = sq ^ (n & 3);
      uint4 v = *(const uint4*)(Bt + (size_t)(col0 + n) * K + k0 + sq * 8);
      *(uint4*)&Blds[(((n << 2) + slot)) << 3] = v;
    }
    __syncthreads();
    short8 af[4], bfr[4];
    #pragma unroll
    for (int i = 0; i < 4; ++i) {
      const int r = wm + i * 16 + l;
      af[i] = *(const short8*)&Alds[(((r << 2) + (q ^ (r & 3)))) << 3];
    }
    #pragma unroll
    for (int j = 0; j < 4; ++j) {
      const int n = wn + j * 16 + l;
      bfr[j] = *(const short8*)&Blds[(((n << 2) + (q ^ (n & 3)))) << 3];
    }
    #pragma unroll
    for (int i = 0; i < 4; ++i)
      #pragma unroll
      for (int j = 0; j < 4; ++j)
        acc[i][j] = __builtin_amdgcn_mfma_f32_16x16x32_bf16(af[i], bfr[j], acc[i][j], 0, 0, 0);
    __syncthreads();
  }
  #pragma unroll
  for (int i = 0; i < 4; ++i) {
    #pragma unroll
    for (int j = 0; j < 4; ++j) {
      #pragma unroll
      for (int r = 0; r < 4; ++r) {
        const int row = row0 + wm + i * 16 + q * 4 + r;
        const int col = col0 + wn + j * 16 + l;
        if constexpr (std::is_same<TC, float>::value)
          C[(size_t)row * N + col] = acc[i][j][r];
        else
          C[(size_t)row * N + col] = f2bf(acc[i][j][r]);
      }
    }
  }
}

// ---------------- weight prep ----------------
// Wp[n'][k], n' = 4*unit + gate; also builds permuted combined bias.
__global__ __launch_bounds__(256) void k_prep_lstm_w(const float* __restrict__ Wih,
                                                     const float* __restrict__ Whh,
                                                     const float* __restrict__ bih,
                                                     const float* __restrict__ bhh,
                                                     u16* __restrict__ Wp,
                                                     float* __restrict__ biasP) {
  const int idx = blockIdx.x * 256 + threadIdx.x;   // 1024*512
  const int np = idx >> 9, k = idx & 511;
  const int u = np >> 2, g = np & 3;
  const int n = g * 256 + u;
  const float v = (k < 256) ? Wih[n * 256 + k] : Whh[n * 256 + (k - 256)];
  Wp[idx] = f2bf(v);
  if (k == 0) biasP[np] = bih[n] + bhh[n];
}

__global__ __launch_bounds__(256) void k_transpose_w(const float* __restrict__ W,
                                                     u16* __restrict__ Wt) {
  const int idx = blockIdx.x * 256 + threadIdx.x;   // 256*256, Wt[n][k]=W[k][n]
  const int n = idx >> 8, k = idx & 255;
  Wt[idx] = f2bf(W[k * 256 + n]);
}

// ---------------- GCN graph-operator precompute ----------------
__global__ __launch_bounds__(256) void k_edge_deg(const int* __restrict__ src,
                                                  const int* __restrict__ dst,
                                                  float* __restrict__ odeg,
                                                  float* __restrict__ ideg) {
  const int e = blockIdx.x * 256 + threadIdx.x;
  atomicAdd(&odeg[src[e]], 1.0f);
  atomicAdd(&ideg[dst[e]], 1.0f);
}

__global__ __launch_bounds__(256) void k_norms(float* __restrict__ d) {
  const int i = blockIdx.x * 256 + threadIdx.x;   // covers sn and dn
  d[i] = rsqrtf(fmaxf(d[i], 1.0f));
}

__global__ __launch_bounds__(256) void k_build_M(const int* __restrict__ src,
                                                 const int* __restrict__ dst,
                                                 const float* __restrict__ sn,
                                                 const float* __restrict__ dn,
                                                 float* __restrict__ Mg) {
  const int e = blockIdx.x * 256 + threadIdx.x;
  const int s = src[e], d = dst[e];
  const int g = s / NPG;
  const int ls = s - g * NPG;
  const int ld = d - g * NPG;
  atomicAdd(&Mg[(size_t)g * 121 + ld * NPG + ls], sn[s] * dn[d]);
}

// X[g,d,:] = act( sum_s M_g[d][s] * Y[g,s,:] + bias )  in-place safe
template<int ACT>
__global__ __launch_bounds__(256) void k_mapply(const u16* __restrict__ Y,
                                                const float* __restrict__ Mg,
                                                const float* __restrict__ bias,
                                                u16* __restrict__ X) {
  __shared__ float Ms[121];
  const int g = blockIdx.x, c = threadIdx.x;
  if (c < 121) Ms[c] = Mg[(size_t)g * 121 + c];
  float y[NPG];
  const u16* yp = Y + (size_t)g * NPG * 256 + c;
  #pragma unroll
  for (int s = 0; s < NPG; ++s) y[s] = bf2f(yp[s * 256]);
  const float bc_ = bias[c];
  __syncthreads();
  u16* xp = X + (size_t)g * NPG * 256 + c;
  #pragma unroll
  for (int d = 0; d < NPG; ++d) {
    float z = bc_;
    #pragma unroll
    for (int s = 0; s < NPG; ++s) z += Ms[d * NPG + s] * y[s];
    if (ACT == 0) z = fmaxf(z, 0.f); else z = fast_tanh(z);
    xp[d * 256] = f2bf(z);
  }
}

// Y3[N,8] = X[N,256] @ W3[256,8]
__global__ __launch_bounds__(256) void k_gemm3(const u16* __restrict__ X,
                                               const float* __restrict__ W3,
                                               float* __restrict__ Y3) {
  __shared__ float W3s[2048];
  const int tid = threadIdx.x;
  for (int i = tid; i < 2048; i += 256) W3s[i] = W3[i];
  __syncthreads();
  const int r = tid >> 3, j = tid & 7;
  const int row = blockIdx.x * 32 + r;
  const u16* xp = X + (size_t)row * 256;
  float acc = 0.f;
  #pragma unroll 4
  for (int k = 0; k < 256; ++k) acc += bf2f(xp[k]) * W3s[k * 8 + j];
  Y3[(size_t)row * 8 + j] = acc;
}

// layer3 M-apply + relu + mean + classify + add LSTM ff output
__global__ __launch_bounds__(256) void k_final(const float* __restrict__ Y3,
                                               const float* __restrict__ Mg,
                                               const float* __restrict__ b3,
                                               const float* __restrict__ Wc,
                                               const float* __restrict__ bc,
                                               const float* __restrict__ ffout,
                                               float* __restrict__ out) {
  __shared__ float Ms[32][121];
  __shared__ float hg[32][8];
  const int tid = threadIdx.x;
  const int g0 = blockIdx.x * 32;
  for (int i = tid; i < 32 * 121; i += 256) Ms[i / 121][i % 121] = Mg[(size_t)g0 * 121 + i];
  const int gl = tid >> 3, j = tid & 7;
  const int g = g0 + gl;
  float y[NPG];
  #pragma unroll
  for (int s = 0; s < NPG; ++s) y[s] = Y3[((size_t)g * NPG + s) * 8 + j];
  __syncthreads();
  const float bj = b3[j];
  float accm = 0.f;
  #pragma unroll
  for (int d = 0; d < NPG; ++d) {
    float z = bj;
    #pragma unroll
    for (int s = 0; s < NPG; ++s) z += Ms[gl][d * NPG + s] * y[s];
    accm += fmaxf(z, 0.f);
  }
  hg[gl][j] = accm * (1.0f / 11.0f);
  __syncthreads();
  if (j < 2) {
    float o = bc[j];
    #pragma unroll
    for (int q = 0; q < 8; ++q) o += hg[gl][q] * Wc[q * 2 + j];
    out[(size_t)g * 2 + j] = o + ffout[(size_t)g * 2 + j];
  }
}

// ---------------------------------------------------------------------------
extern "C" void kernel_launch(void* const* d_in, const int* in_sizes, int n_in,
                              void* d_out, int out_size, void* d_ws, size_t ws_size,
                              hipStream_t stream) {
  (void)in_sizes; (void)n_in; (void)out_size; (void)ws_size;
  const float* feature = (const float*)d_in[0];
  const int*   src     = (const int*)d_in[1];
  const int*   dst     = (const int*)d_in[2];
  const float* W1  = (const float*)d_in[3];
  const float* b1  = (const float*)d_in[4];
  const float* W2  = (const float*)d_in[5];
  const float* b2  = (const float*)d_in[6];
  const float* W3  = (const float*)d_in[7];
  const float* b3  = (const float*)d_in[8];
  const float* Wih = (const float*)d_in[9];
  const float* Whh = (const float*)d_in[10];
  const float* bih = (const float*)d_in[11];
  const float* bhh = (const float*)d_in[12];
  const float* Wf1 = (const float*)d_in[13];
  const float* bf1 = (const float*)d_in[14];
  const float* Wf2 = (const float*)d_in[15];
  const float* bf2 = (const float*)d_in[16];
  const float* Wc  = (const float*)d_in[17];
  const float* bc  = (const float*)d_in[18];
  float* out = (float*)d_out;

  // ---- workspace layout ----
  // [ffout 128K][Wp 1M][Wt1 128K][Wt2 128K][biasP 4K]
  // [ U (GCN only): sn,dn,Mg 9.4M | Abuf(bf16) 92.3M | Y3 5.8M ]
  char* ws = (char*)d_ws;
  float* ffout = (float*)ws;
  u16*   Wp    = (u16*)(ws + 131072);
  u16*   Wt1   = (u16*)(ws + 131072 + 1048576);
  u16*   Wt2   = (u16*)(ws + 131072 + 1048576 + 131072);
  float* biasP = (float*)(ws + 131072 + 1048576 + 131072 + 131072);
  char*  U     = ws + 1572864;
  float* sn    = (float*)U;
  float* dn    = sn + NTOT;
  float* Mg    = dn + NTOT;
  u16*   Abuf  = (u16*)(U + 9371648);                   // 92,274,688
  float* Y3    = (float*)(U + 9371648 + 92274688);      //  5,767,168

  // ---- weight prep ----
  k_prep_lstm_w<<<2048, 256, 0, stream>>>(Wih, Whh, bih, bhh, Wp, biasP);
  k_transpose_w<<<256, 256, 0, stream>>>(W1, Wt1);
  k_transpose_w<<<256, 256, 0, stream>>>(W2, Wt2);

  // ================= LSTM branch: one persistent kernel =================
  lstm_persist<<<BG / 64, 512, 0, stream>>>(feature, Wp, biasP, bf1, Wf1, Wf2, bf2, ffout);

  // ================= GCN branch =================
  hipMemsetAsync(sn, 0, 9371648, stream);                // sn, dn, Mg -> 0
  k_edge_deg<<<EDG / 256, 256, 0, stream>>>(src, dst, sn, dn);
  k_norms<<<(2 * NTOT) / 256, 256, 0, stream>>>(sn);
  k_build_M<<<EDG / 256, 256, 0, stream>>>(src, dst, sn, dn, Mg);

  // layer 1: GEMM (fp32 A -> bf16) + in-place graph mix + relu
  gemm_mfma<0, u16><<<dim3(1, NTOT / 128), 512, 0, stream>>>(feature, nullptr, Wt1, Abuf, 256, 256);
  k_mapply<0><<<BG, 256, 0, stream>>>(Abuf, Mg, b1, Abuf);

  // layer 2: in-place GEMM (full N covered per row-block) + mix + tanh
  gemm_mfma<1, u16><<<dim3(1, NTOT / 128), 512, 0, stream>>>(nullptr, Abuf, Wt2, Abuf, 256, 256);
  k_mapply<1><<<BG, 256, 0, stream>>>(Abuf, Mg, b2, Abuf);

  // layer 3 + pooling + classifier + combine
  k_gemm3<<<NTOT / 32, 256, 0, stream>>>(Abuf, W3, Y3);
  k_final<<<BG / 32, 256, 0, stream>>>(Y3, Mg, b3, Wc, bc, ffout, out);
}